// Round 1
// baseline (283.337 us; speedup 1.0000x reference)
//
#include <hip/hip_runtime.h>
#include <hip/hip_bf16.h>

// Autoregressive LSTM: B=16384, T=60, D=34, E=128, H=64, n_seeds=10
// Persistent block = 32 batch rows x 60 steps. bf16 MFMA (16x16x32),
// weights as B-fragments in registers, activations via LDS.

typedef float f32x4 __attribute__((ext_vector_type(4)));
typedef __bf16 bf16x8 __attribute__((ext_vector_type(8)));
typedef unsigned short u16x8 __attribute__((ext_vector_type(8)));

#define MFMA_BF16(A, B, C) \
    __builtin_amdgcn_mfma_f32_16x16x32_bf16(__builtin_bit_cast(bf16x8, (A)), \
                                            __builtin_bit_cast(bf16x8, (B)), (C), 0, 0, 0)

__device__ __forceinline__ unsigned short f2b(float f) {
    unsigned u = __builtin_bit_cast(unsigned, f);
    u += 0x7fffu + ((u >> 16) & 1u);   // RNE
    return (unsigned short)(u >> 16);
}
__device__ __forceinline__ float sig_(float x) { return 1.0f / (1.0f + __expf(-x)); }
__device__ __forceinline__ float tanh_(float x) {
    float t = __expf(-2.0f * fabsf(x));
    float r = (1.0f - t) / (1.0f + t);
    return copysignf(r, x);
}

__global__ __launch_bounds__(256, 2) void ar_lstm_kernel(
    const float* __restrict__ x,      // (16384,60,34)
    const float* __restrict__ W_enc,  // (128,34)
    const float* __restrict__ b_enc,  // (128)
    const float* __restrict__ W_ih,   // (256,128)
    const float* __restrict__ W_hh,   // (256,64)
    const float* __restrict__ b_ih,   // (256)
    const float* __restrict__ b_hh,   // (256)
    const float* __restrict__ W_dec,  // (34,64)
    const float* __restrict__ b_dec,  // (34)
    float* __restrict__ out)          // (16384,50,34)
{
    // LDS activation tiles; rows padded (+8 bf16 = +16B) so the 16-lane
    // A-fragment column read rotates 16B slots across banks (2-way = free).
    __shared__ __attribute__((aligned(16))) unsigned short x_s[32][136]; // rnn_in (M x 128)
    __shared__ __attribute__((aligned(16))) unsigned short h_s[32][72];  // h      (M x 64)
    __shared__ __attribute__((aligned(16))) unsigned short d_s[32][72];  // enc-in (M x 64, cols>=34 zero-padded)

    const int tid = threadIdx.x;
    const int w  = tid >> 6;   // wave 0..3
    const int l  = tid & 63;
    const int lr = l & 15;     // A-row / D-col lane index
    const int lg = l >> 4;     // lane group 0..3
    const int b0 = blockIdx.x * 32;

    for (int i = tid; i < 32 * 136; i += 256) (&x_s[0][0])[i] = 0;
    for (int i = tid; i < 32 * 72;  i += 256) (&h_s[0][0])[i] = 0;
    for (int i = tid; i < 32 * 72;  i += 256) (&d_s[0][0])[i] = 0;

    // ---- weight fragments in registers (bf16), loaded once ----
    // gates: wave w owns n-tiles {w, w+4, w+8, w+12} -> gate g columns j = w*16+lr
    u16x8 wg[4][6];
    float bias_g[4];
    for (int g = 0; g < 4; ++g) {
        int n = (w + 4 * g) * 16 + lr;
        bias_g[g] = b_ih[n] + b_hh[n];
        for (int kt = 0; kt < 4; ++kt)
            for (int i = 0; i < 8; ++i)
                wg[g][kt][i] = f2b(W_ih[n * 128 + kt * 32 + lg * 8 + i]);
        for (int kt = 0; kt < 2; ++kt)
            for (int i = 0; i < 8; ++i)
                wg[g][4 + kt][i] = f2b(W_hh[n * 64 + kt * 32 + lg * 8 + i]);
    }
    // encoder: wave w owns n-tiles {2w, 2w+1}; K = 34 padded to 64
    u16x8 we[2][2];
    float bias_e[2];
    for (int ntl = 0; ntl < 2; ++ntl) {
        int n = (w * 2 + ntl) * 16 + lr;
        bias_e[ntl] = b_enc[n];
        for (int kt = 0; kt < 2; ++kt)
            for (int i = 0; i < 8; ++i) {
                int k = kt * 32 + lg * 8 + i;
                we[ntl][kt][i] = (k < 34) ? f2b(W_enc[n * 34 + k]) : (unsigned short)0;
            }
    }
    // decoder: wave w owns output cols nd = w*16+lr (valid < 34; waves 2/3 partly zero)
    u16x8 wd[2];
    float bias_d;
    {
        int n = w * 16 + lr;
        bool v = (n < 34);
        bias_d = v ? b_dec[n] : 0.0f;
        for (int kt = 0; kt < 2; ++kt)
            for (int i = 0; i < 8; ++i)
                wd[kt][i] = v ? f2b(W_dec[n * 64 + kt * 32 + lg * 8 + i]) : (unsigned short)0;
    }

    float c_st[2][4];  // c state, fp32, D-fragment layout
    float prev[2][4];  // AR output accumulator, fp32
    for (int mt = 0; mt < 2; ++mt)
        for (int r = 0; r < 4; ++r) { c_st[mt][r] = 0.0f; prev[mt][r] = 0.0f; }

    __syncthreads();

    // encode GEMM: A = d_s (Mx64), out -> relu -> x_s (Mx128)
    auto enc_gemm = [&]() {
        u16x8 ad[2][2];
        for (int mt = 0; mt < 2; ++mt)
            for (int kt = 0; kt < 2; ++kt)
                ad[mt][kt] = *(const u16x8*)&d_s[mt * 16 + lr][kt * 32 + lg * 8];
        for (int mt = 0; mt < 2; ++mt)
            for (int ntl = 0; ntl < 2; ++ntl) {
                f32x4 acc = { bias_e[ntl], bias_e[ntl], bias_e[ntl], bias_e[ntl] };
                acc = MFMA_BF16(ad[mt][0], we[ntl][0], acc);
                acc = MFMA_BF16(ad[mt][1], we[ntl][1], acc);
                for (int r = 0; r < 4; ++r)
                    x_s[mt * 16 + lg * 4 + r][(w * 2 + ntl) * 16 + lr] = f2b(fmaxf(acc[r], 0.0f));
            }
    };

    for (int t = 0; t < 60; ++t) {
        if (t < 10) {
            // stage x[:, t, :34] into d_s (cols 34..63 stay zero)
            for (int idx = tid; idx < 32 * 34; idx += 256) {
                int r = idx / 34;
                int d = idx - r * 34;
                d_s[r][d] = f2b(x[((b0 + r) * 60 + t) * 34 + d]);
            }
            __syncthreads();
            enc_gemm();            // emb_t -> x_s
            __syncthreads();
        }

        // ---- gates GEMM: [x_s | h_s] (Mx192) @ [W_ih|W_hh]^T ----
        u16x8 ax[2][4], ah[2][2];
        for (int mt = 0; mt < 2; ++mt) {
            for (int kt = 0; kt < 4; ++kt)
                ax[mt][kt] = *(const u16x8*)&x_s[mt * 16 + lr][kt * 32 + lg * 8];
            for (int kt = 0; kt < 2; ++kt)
                ah[mt][kt] = *(const u16x8*)&h_s[mt * 16 + lr][kt * 32 + lg * 8];
        }
        f32x4 acc[2][4];
        for (int mt = 0; mt < 2; ++mt)
            for (int g = 0; g < 4; ++g) {
                f32x4 a = { bias_g[g], bias_g[g], bias_g[g], bias_g[g] };
                a = MFMA_BF16(ax[mt][0], wg[g][0], a);
                a = MFMA_BF16(ax[mt][1], wg[g][1], a);
                a = MFMA_BF16(ax[mt][2], wg[g][2], a);
                a = MFMA_BF16(ax[mt][3], wg[g][3], a);
                a = MFMA_BF16(ah[mt][0], wg[g][4], a);
                a = MFMA_BF16(ah[mt][1], wg[g][5], a);
                acc[mt][g] = a;
            }
        __syncthreads();   // all x_s/h_s reads complete before overwrite

        // ---- elementwise LSTM cell (fp32 c-state in registers) ----
        for (int mt = 0; mt < 2; ++mt)
            for (int r = 0; r < 4; ++r) {
                float iv = acc[mt][0][r];
                float fv = acc[mt][1][r];
                float gv = acc[mt][2][r];
                float ov = acc[mt][3][r];
                float cn = sig_(fv) * c_st[mt][r] + sig_(iv) * tanh_(gv);
                float hn = sig_(ov) * tanh_(cn);
                c_st[mt][r] = cn;
                h_s[mt * 16 + lg * 4 + r][w * 16 + lr] = f2b(hn);
            }
        __syncthreads();   // new h visible

        if (t >= 9) {
            // ---- decode GEMM: h (Mx64) @ W_dec^T; all 4 waves (3 real + 1 zero) ----
            u16x8 ah2[2][2];
            for (int mt = 0; mt < 2; ++mt)
                for (int kt = 0; kt < 2; ++kt)
                    ah2[mt][kt] = *(const u16x8*)&h_s[mt * 16 + lr][kt * 32 + lg * 8];
            int nd = w * 16 + lr;
            for (int mt = 0; mt < 2; ++mt) {
                f32x4 a = { bias_d, bias_d, bias_d, bias_d };
                a = MFMA_BF16(ah2[mt][0], wd[0], a);
                a = MFMA_BF16(ah2[mt][1], wd[1], a);
                if (t == 9) {
                    // prev = x[:, 9, :]
                    for (int r = 0; r < 4; ++r)
                        prev[mt][r] = (nd < 34) ? x[((b0 + mt * 16 + lg * 4 + r) * 60 + 9) * 34 + nd] : 0.0f;
                } else {
                    for (int r = 0; r < 4; ++r) {
                        float o = a[r] + prev[mt][r];   // out = dec + prev (fp32 carry)
                        prev[mt][r] = o;
                        if (nd < 34)
                            out[((b0 + mt * 16 + lg * 4 + r) * 50 + (t - 10)) * 34 + nd] = o;
                    }
                }
                // rnn_in = encode(dec): stash dec (not out) for encoder
                for (int r = 0; r < 4; ++r)
                    d_s[mt * 16 + lg * 4 + r][nd] = f2b(a[r]);
            }
            __syncthreads();   // d_s visible
            if (t < 59) enc_gemm();
            __syncthreads();
        }
    }
}

extern "C" void kernel_launch(void* const* d_in, const int* in_sizes, int n_in,
                              void* d_out, int out_size, void* d_ws, size_t ws_size,
                              hipStream_t stream) {
    const float* x     = (const float*)d_in[0];
    const float* W_enc = (const float*)d_in[1];
    const float* b_enc = (const float*)d_in[2];
    const float* W_ih  = (const float*)d_in[3];
    const float* W_hh  = (const float*)d_in[4];
    const float* b_ih  = (const float*)d_in[5];
    const float* b_hh  = (const float*)d_in[6];
    const float* W_dec = (const float*)d_in[7];
    const float* b_dec = (const float*)d_in[8];
    float* out = (float*)d_out;
    // n_seeds (d_in[9]) is compile-time 10 for this problem shape.
    ar_lstm_kernel<<<512, 256, 0, stream>>>(x, W_enc, b_enc, W_ih, W_hh,
                                            b_ih, b_hh, W_dec, b_dec, out);
}

// Round 2
// 260.650 us; speedup vs baseline: 1.0870x; 1.0870x over previous
//
#include <hip/hip_runtime.h>
#include <hip/hip_bf16.h>

// Autoregressive LSTM: B=16384, T=60, D=34, E=128, H=64, n_seeds=10
// Persistent block = 32 batch rows x 60 steps, 4 waves, 512 blocks (2/CU).
// bf16 MFMA 16x16x32; weights in registers; enc∘dec fused into W' = W_enc@W_dec;
// double-buffered h_s -> 2 barriers per AR step.

typedef float f32x4 __attribute__((ext_vector_type(4)));
typedef __bf16 bf16x8 __attribute__((ext_vector_type(8)));
typedef unsigned short u16x8 __attribute__((ext_vector_type(8)));

#define MFMA_BF16(A, B, C) \
    __builtin_amdgcn_mfma_f32_16x16x32_bf16(__builtin_bit_cast(bf16x8, (A)), \
                                            __builtin_bit_cast(bf16x8, (B)), (C), 0, 0, 0)

__device__ __forceinline__ unsigned short f2b(float f) {
    return __builtin_bit_cast(unsigned short, (__bf16)f);   // v_cvt_pk_bf16_f32 path
}
__device__ __forceinline__ float sig_(float x) { return 1.0f / (1.0f + __expf(-x)); }
__device__ __forceinline__ float tanh_(float x) {
    float t = __expf(-2.0f * fabsf(x));
    float r = (1.0f - t) / (1.0f + t);
    return copysignf(r, x);
}

__global__ __launch_bounds__(256, 2) void ar_lstm_kernel(
    const float* __restrict__ x,      // (16384,60,34)
    const float* __restrict__ W_enc,  // (128,34)
    const float* __restrict__ b_enc,  // (128)
    const float* __restrict__ W_ih,   // (256,128)
    const float* __restrict__ W_hh,   // (256,64)
    const float* __restrict__ b_ih,   // (256)
    const float* __restrict__ b_hh,   // (256)
    const float* __restrict__ W_dec,  // (34,64)
    const float* __restrict__ b_dec,  // (34)
    float* __restrict__ out)          // (16384,50,34)
{
    // +8 u16 row pad => 16B bank rotation; 2-way conflicts only (free).
    __shared__ __attribute__((aligned(16))) unsigned short x_s[32][136];    // rnn_in (M x 128)
    __shared__ __attribute__((aligned(16))) unsigned short h_s[2][32][72];  // h double-buffered
    __shared__ __attribute__((aligned(16))) unsigned short d_s[2][32][72];  // seed input staging
    __shared__ __attribute__((aligned(16))) float wdec_f[34][64];           // W_dec fp32 (init only)
    __shared__ float bdec_f[34];

    const int tid = threadIdx.x;
    const int w  = tid >> 6;   // wave 0..3
    const int l  = tid & 63;
    const int lr = l & 15;     // A-row / B-col / D-col lane index
    const int lg = l >> 4;     // lane group 0..3
    const int b0 = blockIdx.x * 32;

    for (int i = tid; i < 32 * 136;    i += 256) (&x_s[0][0])[i] = 0;
    for (int i = tid; i < 2 * 32 * 72; i += 256) (&h_s[0][0][0])[i] = 0;
    for (int i = tid; i < 2 * 32 * 72; i += 256) (&d_s[0][0][0])[i] = 0;
    for (int i = tid; i < 34 * 64;     i += 256) (&wdec_f[0][0])[i] = W_dec[i];
    if (tid < 34) bdec_f[tid] = b_dec[tid];
    // stage seed frame t=0
    for (int e = tid; e < 32 * 34; e += 256) {
        int r = e / 34, d = e - r * 34;
        d_s[0][r][d] = f2b(x[((b0 + r) * 60 + 0) * 34 + d]);
    }

    // ---- weight fragments in registers ----
    // gates: wave w owns hidden cols j = w*16+lr for all 4 gates (n-tiles w+4g)
    u16x8 wg[4][6];
    float bias_g[4];
    for (int g = 0; g < 4; ++g) {
        int n = (w + 4 * g) * 16 + lr;
        bias_g[g] = b_ih[n] + b_hh[n];
        for (int kt = 0; kt < 4; ++kt)
            for (int i = 0; i < 8; ++i)
                wg[g][kt][i] = f2b(W_ih[n * 128 + kt * 32 + lg * 8 + i]);
        for (int kt = 0; kt < 2; ++kt)
            for (int i = 0; i < 8; ++i)
                wg[g][4 + kt][i] = f2b(W_hh[n * 64 + kt * 32 + lg * 8 + i]);
    }
    // seed encoder (K=34 zero-padded to 64)
    u16x8 we[2][2];
    float bias_e[2];
    for (int ntl = 0; ntl < 2; ++ntl) {
        int n = (w * 2 + ntl) * 16 + lr;
        bias_e[ntl] = b_enc[n];
        for (int kt = 0; kt < 2; ++kt)
            for (int i = 0; i < 8; ++i) {
                int k = kt * 32 + lg * 8 + i;
                we[ntl][kt][i] = (k < 34) ? f2b(W_enc[n * 34 + k]) : (unsigned short)0;
            }
    }
    // decoder (cols >= 34 zero; wave 3 never used)
    u16x8 wd[2];
    float bias_d = 0.0f;
    {
        int n = w * 16 + lr;
        bool v = (w < 3) && (n < 34);
        bias_d = v ? b_dec[n] : 0.0f;
        for (int kt = 0; kt < 2; ++kt)
            for (int i = 0; i < 8; ++i)
                wd[kt][i] = v ? f2b(W_dec[n * 64 + kt * 32 + lg * 8 + i]) : (unsigned short)0;
    }

    __syncthreads();  // wdec_f/bdec_f staged, LDS zeroed, d_s[0] staged

    // ---- fused W' = W_enc @ W_dec (128x64), b' = b_enc + W_enc @ b_dec ----
    u16x8 wf[2][2];
    float bias_f[2];
    for (int ntl = 0; ntl < 2; ++ntl) {
        int n = (w * 2 + ntl) * 16 + lr;
        f32x4 av0 = {0,0,0,0}, av1 = {0,0,0,0}, av2 = {0,0,0,0}, av3 = {0,0,0,0};
        float bacc = b_enc[n];
        for (int j = 0; j < 34; ++j) {
            float wej = W_enc[n * 34 + j];
            bacc += wej * bdec_f[j];
            av0 += wej * *(const f32x4*)&wdec_f[j][lg * 8];
            av1 += wej * *(const f32x4*)&wdec_f[j][lg * 8 + 4];
            av2 += wej * *(const f32x4*)&wdec_f[j][32 + lg * 8];
            av3 += wej * *(const f32x4*)&wdec_f[j][32 + lg * 8 + 4];
        }
        bias_f[ntl] = bacc;
        for (int i = 0; i < 4; ++i) {
            wf[ntl][0][i]     = f2b(av0[i]);
            wf[ntl][0][4 + i] = f2b(av1[i]);
            wf[ntl][1][i]     = f2b(av2[i]);
            wf[ntl][1][4 + i] = f2b(av3[i]);
        }
    }

    float c_st[2][4], prev[2][4];
    for (int mt = 0; mt < 2; ++mt)
        for (int r = 0; r < 4; ++r) { c_st[mt][r] = 0.0f; prev[mt][r] = 0.0f; }

    for (int t = 0; t < 60; ++t) {
        const int hw = t & 1;       // cell writes h_s[hw]
        const int hr = hw ^ 1;      // gates read h_s[hr]

        if (t < 10) {
            // seed encode: x_s = relu(d_s[hw] @ we^T); prefetch next seed frame
            u16x8 ad[2][2];
            for (int mt = 0; mt < 2; ++mt)
                for (int kt = 0; kt < 2; ++kt)
                    ad[mt][kt] = *(const u16x8*)&d_s[hw][mt * 16 + lr][kt * 32 + lg * 8];
            for (int mt = 0; mt < 2; ++mt)
                for (int ntl = 0; ntl < 2; ++ntl) {
                    f32x4 a = {bias_e[ntl], bias_e[ntl], bias_e[ntl], bias_e[ntl]};
                    a = MFMA_BF16(ad[mt][0], we[ntl][0], a);
                    a = MFMA_BF16(ad[mt][1], we[ntl][1], a);
                    for (int r = 0; r < 4; ++r)
                        x_s[mt * 16 + lg * 4 + r][(w * 2 + ntl) * 16 + lr] = f2b(fmaxf(a[r], 0.0f));
                }
            if (t + 1 < 10)
                for (int e = tid; e < 32 * 34; e += 256) {
                    int r = e / 34, d = e - r * 34;
                    d_s[hr][r][d] = f2b(x[((b0 + r) * 60 + (t + 1)) * 34 + d]);
                }
            __syncthreads();
        }

        // ---- gates GEMM + cell, one 16-row tile at a time ----
        for (int mt = 0; mt < 2; ++mt) {
            u16x8 ax[4], ah[2];
            for (int kt = 0; kt < 4; ++kt)
                ax[kt] = *(const u16x8*)&x_s[mt * 16 + lr][kt * 32 + lg * 8];
            for (int kt = 0; kt < 2; ++kt)
                ah[kt] = *(const u16x8*)&h_s[hr][mt * 16 + lr][kt * 32 + lg * 8];
            f32x4 acc[4];
            for (int g = 0; g < 4; ++g) {
                f32x4 a = {bias_g[g], bias_g[g], bias_g[g], bias_g[g]};
                a = MFMA_BF16(ax[0], wg[g][0], a);
                a = MFMA_BF16(ax[1], wg[g][1], a);
                a = MFMA_BF16(ax[2], wg[g][2], a);
                a = MFMA_BF16(ax[3], wg[g][3], a);
                a = MFMA_BF16(ah[0], wg[g][4], a);
                a = MFMA_BF16(ah[1], wg[g][5], a);
                acc[g] = a;
            }
            for (int r = 0; r < 4; ++r) {
                float cn = sig_(acc[1][r]) * c_st[mt][r] + sig_(acc[0][r]) * tanh_(acc[2][r]);
                float hn = sig_(acc[3][r]) * tanh_(cn);
                c_st[mt][r] = cn;
                h_s[hw][mt * 16 + lg * 4 + r][w * 16 + lr] = f2b(hn);
            }
        }
        __syncthreads();

        if (t >= 9) {
            // dec (out) + fused enc' (next rnn_in), both from h_s[hw] A-frags
            u16x8 ah2[2][2];
            for (int mt = 0; mt < 2; ++mt)
                for (int kt = 0; kt < 2; ++kt)
                    ah2[mt][kt] = *(const u16x8*)&h_s[hw][mt * 16 + lr][kt * 32 + lg * 8];
            const int nd = w * 16 + lr;
            if (t == 9) {
                if (w < 3 && nd < 34)
                    for (int mt = 0; mt < 2; ++mt)
                        for (int r = 0; r < 4; ++r)
                            prev[mt][r] = x[((b0 + mt * 16 + lg * 4 + r) * 60 + 9) * 34 + nd];
            } else if (w < 3) {
                for (int mt = 0; mt < 2; ++mt) {
                    f32x4 a = {bias_d, bias_d, bias_d, bias_d};
                    a = MFMA_BF16(ah2[mt][0], wd[0], a);
                    a = MFMA_BF16(ah2[mt][1], wd[1], a);
                    if (nd < 34)
                        for (int r = 0; r < 4; ++r) {
                            float o = a[r] + prev[mt][r];
                            prev[mt][r] = o;
                            out[((b0 + mt * 16 + lg * 4 + r) * 50 + (t - 10)) * 34 + nd] = o;
                        }
                }
            }
            if (t < 59) {
                for (int mt = 0; mt < 2; ++mt)
                    for (int ntl = 0; ntl < 2; ++ntl) {
                        f32x4 a = {bias_f[ntl], bias_f[ntl], bias_f[ntl], bias_f[ntl]};
                        a = MFMA_BF16(ah2[mt][0], wf[ntl][0], a);
                        a = MFMA_BF16(ah2[mt][1], wf[ntl][1], a);
                        for (int r = 0; r < 4; ++r)
                            x_s[mt * 16 + lg * 4 + r][(w * 2 + ntl) * 16 + lr] = f2b(fmaxf(a[r], 0.0f));
                    }
            }
            __syncthreads();
        }
    }
}

extern "C" void kernel_launch(void* const* d_in, const int* in_sizes, int n_in,
                              void* d_out, int out_size, void* d_ws, size_t ws_size,
                              hipStream_t stream) {
    const float* x     = (const float*)d_in[0];
    const float* W_enc = (const float*)d_in[1];
    const float* b_enc = (const float*)d_in[2];
    const float* W_ih  = (const float*)d_in[3];
    const float* W_hh  = (const float*)d_in[4];
    const float* b_ih  = (const float*)d_in[5];
    const float* b_hh  = (const float*)d_in[6];
    const float* W_dec = (const float*)d_in[7];
    const float* b_dec = (const float*)d_in[8];
    float* out = (float*)d_out;
    // n_seeds (d_in[9]) is compile-time 10 for this problem shape.
    ar_lstm_kernel<<<512, 256, 0, stream>>>(x, W_enc, b_enc, W_ih, W_hh,
                                            b_ih, b_hh, W_dec, b_dec, out);
}

// Round 3
// 182.100 us; speedup vs baseline: 1.5559x; 1.4314x over previous
//
#include <hip/hip_runtime.h>
#include <hip/hip_bf16.h>

// Autoregressive LSTM: B=16384, T=60, D=34, E=128, H=64, n_seeds=10
// Persistent block = 32 batch rows x 60 steps, 4 waves, 512 blocks (2/CU).
// bf16 MFMA 16x16x32; weights in registers; enc∘dec fused into W' = W_enc@W_dec;
// double-buffered h_s -> 2 barriers per AR step.
// R3: cell math via native v_exp_f32/v_rcp_f32 (no IEEE division), tanh = 2σ(2x)−1.

typedef float f32x4 __attribute__((ext_vector_type(4)));
typedef __bf16 bf16x8 __attribute__((ext_vector_type(8)));
typedef unsigned short u16x8 __attribute__((ext_vector_type(8)));

#define MFMA_BF16(A, B, C) \
    __builtin_amdgcn_mfma_f32_16x16x32_bf16(__builtin_bit_cast(bf16x8, (A)), \
                                            __builtin_bit_cast(bf16x8, (B)), (C), 0, 0, 0)

__device__ __forceinline__ unsigned short f2b(float f) {
    return __builtin_bit_cast(unsigned short, (__bf16)f);
}
__device__ __forceinline__ float exp2_(float x) {
#if __has_builtin(__builtin_amdgcn_exp2f)
    return __builtin_amdgcn_exp2f(x);      // v_exp_f32
#else
    return __exp2f(x);
#endif
}
__device__ __forceinline__ float rcp_(float x) {
    return __builtin_amdgcn_rcpf(x);       // v_rcp_f32 (~1 ulp, no div expansion)
}
__device__ __forceinline__ float sig_(float x) {
    // 1/(1+2^(-x*log2e)) : mul, exp, add, rcp
    return rcp_(1.0f + exp2_(-1.44269504f * x));
}
__device__ __forceinline__ float tanh_(float x) {
    // 2σ(2x)−1 : mul, exp, add, rcp, fma. Saturates correctly (exp2→inf→rcp→0).
    return __builtin_fmaf(2.0f, rcp_(1.0f + exp2_(-2.88539008f * x)), -1.0f);
}

__global__ __launch_bounds__(256, 2) void ar_lstm_kernel(
    const float* __restrict__ x,      // (16384,60,34)
    const float* __restrict__ W_enc,  // (128,34)
    const float* __restrict__ b_enc,  // (128)
    const float* __restrict__ W_ih,   // (256,128)
    const float* __restrict__ W_hh,   // (256,64)
    const float* __restrict__ b_ih,   // (256)
    const float* __restrict__ b_hh,   // (256)
    const float* __restrict__ W_dec,  // (34,64)
    const float* __restrict__ b_dec,  // (34)
    float* __restrict__ out)          // (16384,50,34)
{
    // +8 u16 row pad => 16B bank rotation; 2-way conflicts only (free).
    __shared__ __attribute__((aligned(16))) unsigned short x_s[32][136];    // rnn_in (M x 128)
    __shared__ __attribute__((aligned(16))) unsigned short h_s[2][32][72];  // h double-buffered
    __shared__ __attribute__((aligned(16))) unsigned short d_s[2][32][72];  // seed input staging
    __shared__ __attribute__((aligned(16))) float wdec_f[34][64];           // W_dec fp32 (init only)
    __shared__ float bdec_f[34];

    const int tid = threadIdx.x;
    const int w  = tid >> 6;   // wave 0..3
    const int l  = tid & 63;
    const int lr = l & 15;     // A-row / B-col / D-col lane index
    const int lg = l >> 4;     // lane group 0..3
    const int b0 = blockIdx.x * 32;

    for (int i = tid; i < 32 * 136;    i += 256) (&x_s[0][0])[i] = 0;
    for (int i = tid; i < 2 * 32 * 72; i += 256) (&h_s[0][0][0])[i] = 0;
    for (int i = tid; i < 2 * 32 * 72; i += 256) (&d_s[0][0][0])[i] = 0;
    for (int i = tid; i < 34 * 64;     i += 256) (&wdec_f[0][0])[i] = W_dec[i];
    if (tid < 34) bdec_f[tid] = b_dec[tid];
    // stage seed frame t=0
    for (int e = tid; e < 32 * 34; e += 256) {
        int r = e / 34, d = e - r * 34;
        d_s[0][r][d] = f2b(x[((b0 + r) * 60 + 0) * 34 + d]);
    }

    // ---- weight fragments in registers ----
    // gates: wave w owns hidden cols j = w*16+lr for all 4 gates (n-tiles w+4g)
    u16x8 wg[4][6];
    float bias_g[4];
    for (int g = 0; g < 4; ++g) {
        int n = (w + 4 * g) * 16 + lr;
        bias_g[g] = b_ih[n] + b_hh[n];
        for (int kt = 0; kt < 4; ++kt)
            for (int i = 0; i < 8; ++i)
                wg[g][kt][i] = f2b(W_ih[n * 128 + kt * 32 + lg * 8 + i]);
        for (int kt = 0; kt < 2; ++kt)
            for (int i = 0; i < 8; ++i)
                wg[g][4 + kt][i] = f2b(W_hh[n * 64 + kt * 32 + lg * 8 + i]);
    }
    // seed encoder (K=34 zero-padded to 64)
    u16x8 we[2][2];
    float bias_e[2];
    for (int ntl = 0; ntl < 2; ++ntl) {
        int n = (w * 2 + ntl) * 16 + lr;
        bias_e[ntl] = b_enc[n];
        for (int kt = 0; kt < 2; ++kt)
            for (int i = 0; i < 8; ++i) {
                int k = kt * 32 + lg * 8 + i;
                we[ntl][kt][i] = (k < 34) ? f2b(W_enc[n * 34 + k]) : (unsigned short)0;
            }
    }
    // decoder (cols >= 34 zero; wave 3 never used)
    u16x8 wd[2];
    float bias_d = 0.0f;
    {
        int n = w * 16 + lr;
        bool v = (w < 3) && (n < 34);
        bias_d = v ? b_dec[n] : 0.0f;
        for (int kt = 0; kt < 2; ++kt)
            for (int i = 0; i < 8; ++i)
                wd[kt][i] = v ? f2b(W_dec[n * 64 + kt * 32 + lg * 8 + i]) : (unsigned short)0;
    }

    __syncthreads();  // wdec_f/bdec_f staged, LDS zeroed, d_s[0] staged

    // ---- fused W' = W_enc @ W_dec (128x64), b' = b_enc + W_enc @ b_dec ----
    u16x8 wf[2][2];
    float bias_f[2];
    for (int ntl = 0; ntl < 2; ++ntl) {
        int n = (w * 2 + ntl) * 16 + lr;
        f32x4 av0 = {0,0,0,0}, av1 = {0,0,0,0}, av2 = {0,0,0,0}, av3 = {0,0,0,0};
        float bacc = b_enc[n];
        for (int j = 0; j < 34; ++j) {
            float wej = W_enc[n * 34 + j];
            bacc += wej * bdec_f[j];
            av0 += wej * *(const f32x4*)&wdec_f[j][lg * 8];
            av1 += wej * *(const f32x4*)&wdec_f[j][lg * 8 + 4];
            av2 += wej * *(const f32x4*)&wdec_f[j][32 + lg * 8];
            av3 += wej * *(const f32x4*)&wdec_f[j][32 + lg * 8 + 4];
        }
        bias_f[ntl] = bacc;
        for (int i = 0; i < 4; ++i) {
            wf[ntl][0][i]     = f2b(av0[i]);
            wf[ntl][0][4 + i] = f2b(av1[i]);
            wf[ntl][1][i]     = f2b(av2[i]);
            wf[ntl][1][4 + i] = f2b(av3[i]);
        }
    }

    float c_st[2][4], prev[2][4];
    for (int mt = 0; mt < 2; ++mt)
        for (int r = 0; r < 4; ++r) { c_st[mt][r] = 0.0f; prev[mt][r] = 0.0f; }

    for (int t = 0; t < 60; ++t) {
        const int hw = t & 1;       // cell writes h_s[hw]
        const int hr = hw ^ 1;      // gates read h_s[hr]

        if (t < 10) {
            // seed encode: x_s = relu(d_s[hw] @ we^T); prefetch next seed frame
            u16x8 ad[2][2];
            for (int mt = 0; mt < 2; ++mt)
                for (int kt = 0; kt < 2; ++kt)
                    ad[mt][kt] = *(const u16x8*)&d_s[hw][mt * 16 + lr][kt * 32 + lg * 8];
            for (int mt = 0; mt < 2; ++mt)
                for (int ntl = 0; ntl < 2; ++ntl) {
                    f32x4 a = {bias_e[ntl], bias_e[ntl], bias_e[ntl], bias_e[ntl]};
                    a = MFMA_BF16(ad[mt][0], we[ntl][0], a);
                    a = MFMA_BF16(ad[mt][1], we[ntl][1], a);
                    for (int r = 0; r < 4; ++r)
                        x_s[mt * 16 + lg * 4 + r][(w * 2 + ntl) * 16 + lr] = f2b(fmaxf(a[r], 0.0f));
                }
            if (t + 1 < 10)
                for (int e = tid; e < 32 * 34; e += 256) {
                    int r = e / 34, d = e - r * 34;
                    d_s[hr][r][d] = f2b(x[((b0 + r) * 60 + (t + 1)) * 34 + d]);
                }
            __syncthreads();
        }

        // ---- gates GEMM + cell, one 16-row tile at a time ----
        for (int mt = 0; mt < 2; ++mt) {
            u16x8 ax[4], ah[2];
            for (int kt = 0; kt < 4; ++kt)
                ax[kt] = *(const u16x8*)&x_s[mt * 16 + lr][kt * 32 + lg * 8];
            for (int kt = 0; kt < 2; ++kt)
                ah[kt] = *(const u16x8*)&h_s[hr][mt * 16 + lr][kt * 32 + lg * 8];
            f32x4 acc[4];
            for (int g = 0; g < 4; ++g) {
                f32x4 a = {bias_g[g], bias_g[g], bias_g[g], bias_g[g]};
                a = MFMA_BF16(ax[0], wg[g][0], a);
                a = MFMA_BF16(ax[1], wg[g][1], a);
                a = MFMA_BF16(ax[2], wg[g][2], a);
                a = MFMA_BF16(ax[3], wg[g][3], a);
                a = MFMA_BF16(ah[0], wg[g][4], a);
                a = MFMA_BF16(ah[1], wg[g][5], a);
                acc[g] = a;
            }
            for (int r = 0; r < 4; ++r) {
                float cn = sig_(acc[1][r]) * c_st[mt][r] + sig_(acc[0][r]) * tanh_(acc[2][r]);
                float hn = sig_(acc[3][r]) * tanh_(cn);
                c_st[mt][r] = cn;
                h_s[hw][mt * 16 + lg * 4 + r][w * 16 + lr] = f2b(hn);
            }
        }
        __syncthreads();

        if (t >= 9) {
            // dec (out) + fused enc' (next rnn_in), both from h_s[hw] A-frags
            u16x8 ah2[2][2];
            for (int mt = 0; mt < 2; ++mt)
                for (int kt = 0; kt < 2; ++kt)
                    ah2[mt][kt] = *(const u16x8*)&h_s[hw][mt * 16 + lr][kt * 32 + lg * 8];
            const int nd = w * 16 + lr;
            if (t == 9) {
                if (w < 3 && nd < 34)
                    for (int mt = 0; mt < 2; ++mt)
                        for (int r = 0; r < 4; ++r)
                            prev[mt][r] = x[((b0 + mt * 16 + lg * 4 + r) * 60 + 9) * 34 + nd];
            } else if (w < 3) {
                for (int mt = 0; mt < 2; ++mt) {
                    f32x4 a = {bias_d, bias_d, bias_d, bias_d};
                    a = MFMA_BF16(ah2[mt][0], wd[0], a);
                    a = MFMA_BF16(ah2[mt][1], wd[1], a);
                    if (nd < 34)
                        for (int r = 0; r < 4; ++r) {
                            float o = a[r] + prev[mt][r];
                            prev[mt][r] = o;
                            out[((b0 + mt * 16 + lg * 4 + r) * 50 + (t - 10)) * 34 + nd] = o;
                        }
                }
            }
            if (t < 59) {
                for (int mt = 0; mt < 2; ++mt)
                    for (int ntl = 0; ntl < 2; ++ntl) {
                        f32x4 a = {bias_f[ntl], bias_f[ntl], bias_f[ntl], bias_f[ntl]};
                        a = MFMA_BF16(ah2[mt][0], wf[ntl][0], a);
                        a = MFMA_BF16(ah2[mt][1], wf[ntl][1], a);
                        for (int r = 0; r < 4; ++r)
                            x_s[mt * 16 + lg * 4 + r][(w * 2 + ntl) * 16 + lr] = f2b(fmaxf(a[r], 0.0f));
                    }
            }
            __syncthreads();
        }
    }
}

extern "C" void kernel_launch(void* const* d_in, const int* in_sizes, int n_in,
                              void* d_out, int out_size, void* d_ws, size_t ws_size,
                              hipStream_t stream) {
    const float* x     = (const float*)d_in[0];
    const float* W_enc = (const float*)d_in[1];
    const float* b_enc = (const float*)d_in[2];
    const float* W_ih  = (const float*)d_in[3];
    const float* W_hh  = (const float*)d_in[4];
    const float* b_ih  = (const float*)d_in[5];
    const float* b_hh  = (const float*)d_in[6];
    const float* W_dec = (const float*)d_in[7];
    const float* b_dec = (const float*)d_in[8];
    float* out = (float*)d_out;
    // n_seeds (d_in[9]) is compile-time 10 for this problem shape.
    ar_lstm_kernel<<<512, 256, 0, stream>>>(x, W_enc, b_enc, W_ih, W_hh,
                                            b_ih, b_hh, W_dec, b_dec, out);
}